// Round 9
// baseline (106.319 us; speedup 1.0000x reference)
//
#include <hip/hip_runtime.h>
#include <math.h>

#define S_ 8
#define J_ 4
#define D_ 4
#define P_ 3
#define N_ 1024
#define BG_ 32
#define BU_ 32
#define MG_ 10
#define MU_ 32

#define NBLK 512

static constexpr float PI_F = 3.14159265358979323846f;

// workspace float offsets
#define COEF_OFF   0        // [s][j][bu][d][2] = 8192 floats
#define FLAG1_OFF  8192     // 512 ints
#define FLAG2_OFF  8704     // 512 ints

#define MAGIC1 0x7FA3C851
#define MAGIC2 0x39D2B4E7

// ================= single kernel: coef -> tables -> 2x(can+final) ============
// 512 blocks x 256 thr; block b owns n = b and n = b+512, plus coef values
// v in [b*8, b*8+8).  Handshake: per-block MAGIC flags; coef is idempotent
// across replays so stale-MAGIC fast path is correct.
__global__ __launch_bounds__(256, 4) void one_kernel(
    const float* __restrict__ ts,     const float* __restrict__ alphas,
    const float* __restrict__ pgs,    const float* __restrict__ zgs,
    const float* __restrict__ thetag, const float* __restrict__ betag,
    const float* __restrict__ wg,     const float* __restrict__ qg,
    const float* __restrict__ pus,    const float* __restrict__ zus,
    const float* __restrict__ thetau, const float* __restrict__ betau,
    const float* __restrict__ wu,     const float* __restrict__ qu,
    const float* __restrict__ ampu_p, const float* __restrict__ log_amps,
    const float* __restrict__ W,      float* __restrict__ ws,
    float* __restrict__ out)
{
    __shared__ float sc1[D_*P_][BG_][S_];   // 3072
    __shared__ float sc2[D_*P_][BG_][S_];   // 3072
    __shared__ float sqg[D_*P_][MG_][S_];   // 960
    __shared__ float squ[D_][S_][MU_];      // 1024
    __shared__ float stg[D_*P_][BG_];       // 384
    __shared__ float szg[P_][MG_];          // 30
    __shared__ float szu[P_][MU_];          // 96
    __shared__ float scan[S_][D_];          // 32

    int t   = threadIdx.x;
    int bid = blockIdx.x;
    float ampu = ampu_p[0];

    int* flags1 = (int*)(ws + FLAG1_OFF);
    int* flags2 = (int*)(ws + FLAG2_OFF);

    // ---------- phase 0: produce 8 coef values (1 wave per value) ----------
    {
        int lane = t & 63;
        int wv   = t >> 6;
        #pragma unroll 1
        for (int i = 0; i < 2; ++i) {
            int v  = bid*8 + wv*2 + i;
            int bu = v & 31, d = (v >> 5) & 3, j = (v >> 7) & 3, s = v >> 9;
            float G3r = 1.f, G3i = 0.f;
            #pragma unroll 1
            for (int p = 0; p < P_; ++p) {
                float alpha = alphas[d*P_ + p], pg = pgs[d*P_ + p];
                float om    = thetau[((s*J_ + j)*P_ + p)*BU_ + bu];
                float A = alpha + pg, invA = 1.f / A;
                float gr = 0.f, gi = 0.f, cr = 0.f, ci = 0.f;
                if (lane < BG_) {
                    float inv4a = 0.25f / alpha;
                    float pref  = 0.5f * sqrtf(PI_F / alpha);
                    float th = thetag[(d*P_ + p)*BG_ + lane];
                    float dm = th - om, dpl = th + om;
                    float e1 = __expf(-dm*dm*inv4a);
                    float e2 = __expf(-dpl*dpl*inv4a);
                    float be = betag[((s*D_ + d)*P_ + p)*BG_ + lane];
                    float w  = wg   [((s*D_ + d)*P_ + p)*BG_ + lane];
                    float sb, cb; __sincosf(be, &sb, &cb);
                    gr = pref * w * (e1 + e2) * cb;
                    gi = pref * w * (e1 - e2) * sb;
                } else if (lane < BG_ + MG_) {
                    int g = lane - BG_;
                    float cc = sqrtf(PI_F * invA);
                    float z  = zgs[g*P_ + p];
                    float mu = pg * z * invA;
                    float rg = alpha * pg * z * z * invA;
                    float cg = cc * __expf(-rg);
                    float qv = qg[((s*D_ + d)*P_ + p)*MG_ + g];
                    float sm, cm; __sincosf(om * mu, &sm, &cm);
                    cr =  qv * cg * cm;
                    ci = -qv * cg * sm;
                }
                #pragma unroll
                for (int off = 32; off; off >>= 1) {
                    gr += __shfl_xor(gr, off, 64);
                    gi += __shfl_xor(gi, off, 64);
                    cr += __shfl_xor(cr, off, 64);
                    ci += __shfl_xor(ci, off, 64);
                }
                float decay = __expf(-om*om*0.25f*invA);
                float Gr = gr + decay * cr;
                float Gi = gi + decay * ci;
                float nr = G3r*Gr - G3i*Gi;
                float ni = G3r*Gi + G3i*Gr;
                G3r = nr; G3i = ni;
            }
            if (lane == 0) {
                float bv = betau[(s*J_ + j)*BU_ + bu];
                float wv2 = wu  [(s*J_ + j)*BU_ + bu];
                float sbu, cbu; __sincosf(bv, &sbu, &cbu);
                float cuR = wv2 * cbu, cuI = wv2 * sbu;
                float amp = ampu * __expf(log_amps[d*J_ + j]);
                int base = (((s*J_ + j)*BU_ + bu)*D_ + d) * 2;
                ws[COEF_OFF + base    ] = amp * (cuR*G3r - cuI*G3i);
                ws[COEF_OFF + base + 1] = amp * (cuR*G3i + cuI*G3r);
            }
        }
    }
    __threadfence();          // device-scope release of this thread's stores
    __syncthreads();
    if (t == 0) {
        __hip_atomic_store(&flags1[bid], MAGIC1, __ATOMIC_RELEASE, __HIP_MEMORY_SCOPE_AGENT);
        __hip_atomic_store(&flags2[bid], MAGIC2, __ATOMIC_RELEASE, __HIP_MEMORY_SCOPE_AGENT);
    }

    // ---------- phase 1: build all-d LDS tables ----------
    for (int i = t; i < D_*P_*BG_*S_; i += 256) {   // sc1/sc2 [dp][b][s]
        int s = i & 7, b = (i >> 3) & 31, dp = i >> 8;
        int d = dp / P_, p = dp % P_;
        float alpha = alphas[dp];
        float Bm = alpha + pus[p];
        float th = thetag[dp*BG_ + b];
        float spec = sqrtf(PI_F / Bm) * __expf(-th*th*0.25f/Bm);
        float be = betag[((s*D_ + d)*P_ + p)*BG_ + b];
        float w  = wg   [((s*D_ + d)*P_ + p)*BG_ + b];
        float sb, cb; __sincosf(be, &sb, &cb);
        sc1[dp][b][s] = w * cb * spec;
        sc2[dp][b][s] = w * sb * spec;
    }
    for (int i = t; i < D_*P_*MG_*S_; i += 256) {   // sqg [dp][g][s]
        int s = i & 7, g = (i >> 3) % MG_, dp = (i >> 3) / MG_;
        int d = dp / P_, p = dp % P_;
        sqg[dp][g][s] = qg[((s*D_ + d)*P_ + p)*MG_ + g];
    }
    for (int i = t; i < D_*S_*MU_; i += 256) {      // squ [d][s][m]
        int m = i & 31, s = (i >> 5) & 7, d = i >> 8;
        float acc = 0.f;
        #pragma unroll
        for (int j = 0; j < J_; ++j)
            acc += __expf(log_amps[d*J_ + j]) * qu[(s*J_ + j)*MU_ + m];
        squ[d][s][m] = ampu * acc;
    }
    for (int i = t; i < D_*P_*BG_; i += 256) ((float*)stg)[i] = thetag[i];
    if (t < P_*MG_) { int p = t / MG_, g = t % MG_; szg[p][g] = zgs[g*P_ + p]; }
    if (t >= 64 && t < 64 + P_*MU_) {
        int i = t - 64; int p = i >> 5, m = i & 31;
        szu[p][m] = zus[m*P_ + p];
    }
    __syncthreads();

    bool polled = false;

    #pragma unroll 1
    for (int rep = 0; rep < 2; ++rep) {
        int n = bid + rep * NBLK;
        float t0 = ts[n*P_], t1 = ts[n*P_ + 1], t2 = ts[n*P_ + 2];

        // ---------- can phase: t = d*64 + q*32 + m ----------
        {
            int m = t & 31, q = (t >> 5) & 1, d = t >> 6;
            float tsn[P_] = {t0, t1, t2};

            float pr0=1.f,pr1=1.f,pr2=1.f,pr3=1.f,pr4=1.f,pr5=1.f,pr6=1.f,pr7=1.f;

            #pragma unroll 1
            for (int p = 0; p < P_; ++p) {
                int dp = d*P_ + p;
                float alpha = alphas[dp], pg = pgs[dp], pu = pus[p];
                float Bm = alpha + pu, invB = 1.f / Bm;
                float kmp = pu * invB;
                float krp = alpha * pu * invB;
                float Cm = Bm + pg, invC = 1.f / Cm;
                float ksc = sqrtf(PI_F * invC);
                float kbc = Bm * pg * invC;

                float c  = tsn[p] - szu[p][m];
                float mp = kmp * c;
                float E  = __expf(-krp * c * c);

                float a0=0.f,a1=0.f,a2=0.f,a3=0.f,a4=0.f,a5=0.f,a6=0.f,a7=0.f;
                int b0 = q * 16;
                #pragma unroll 4
                for (int bb = 0; bb < 16; ++bb) {
                    int b = b0 + bb;
                    float sx, cx; __sincosf(stg[dp][b] * mp, &sx, &cx);
                    const float4* c1v = (const float4*)&sc1[dp][b][0];
                    const float4* c2v = (const float4*)&sc2[dp][b][0];
                    float4 u0 = c1v[0], u1 = c1v[1];
                    float4 v0 = c2v[0], v1 = c2v[1];
                    a0 += u0.x*cx - v0.x*sx;  a1 += u0.y*cx - v0.y*sx;
                    a2 += u0.z*cx - v0.z*sx;  a3 += u0.w*cx - v0.w*sx;
                    a4 += u1.x*cx - v1.x*sx;  a5 += u1.y*cx - v1.y*sx;
                    a6 += u1.z*cx - v1.z*sx;  a7 += u1.w*cx - v1.w*sx;
                }
                int g0 = q * 5;
                #pragma unroll 1
                for (int gg = 0; gg < 5; ++gg) {
                    int g = g0 + gg;
                    float diff = mp - szg[p][g];
                    float v = ksc * __expf(-kbc*diff*diff);
                    const float4* qv = (const float4*)&sqg[dp][g][0];
                    float4 q0 = qv[0], q1 = qv[1];
                    a0 += q0.x*v; a1 += q0.y*v; a2 += q0.z*v; a3 += q0.w*v;
                    a4 += q1.x*v; a5 += q1.y*v; a6 += q1.z*v; a7 += q1.w*v;
                }
                a0 += __shfl_xor(a0, 32, 64); a1 += __shfl_xor(a1, 32, 64);
                a2 += __shfl_xor(a2, 32, 64); a3 += __shfl_xor(a3, 32, 64);
                a4 += __shfl_xor(a4, 32, 64); a5 += __shfl_xor(a5, 32, 64);
                a6 += __shfl_xor(a6, 32, 64); a7 += __shfl_xor(a7, 32, 64);
                pr0 *= E*a0; pr1 *= E*a1; pr2 *= E*a2; pr3 *= E*a3;
                pr4 *= E*a4; pr5 *= E*a5; pr6 *= E*a6; pr7 *= E*a7;
            }

            float prod[S_] = {pr0,pr1,pr2,pr3,pr4,pr5,pr6,pr7};
            int s0 = q * 4;
            #pragma unroll
            for (int ss = 0; ss < 4; ++ss) {
                int s = s0 + ss;
                float val = squ[d][s][m] * prod[s];
                #pragma unroll
                for (int off = 16; off; off >>= 1) val += __shfl_xor(val, off, 32);
                if (m == 0) scan[s][d] = val;
            }
        }

        // ---------- handshake (first rep only; instant on later calls) ------
        if (!polled) {
            int i1 = t, i2 = t + 256;
            for (int it = 0; it < (1 << 16); ++it) {
                bool ok =
                    __hip_atomic_load(&flags1[i1], __ATOMIC_RELAXED, __HIP_MEMORY_SCOPE_AGENT) == MAGIC1 &&
                    __hip_atomic_load(&flags1[i2], __ATOMIC_RELAXED, __HIP_MEMORY_SCOPE_AGENT) == MAGIC1 &&
                    __hip_atomic_load(&flags2[i1], __ATOMIC_RELAXED, __HIP_MEMORY_SCOPE_AGENT) == MAGIC2 &&
                    __hip_atomic_load(&flags2[i2], __ATOMIC_RELAXED, __HIP_MEMORY_SCOPE_AGENT) == MAGIC2;
                if (ok) break;
                __builtin_amdgcn_s_sleep(4);
            }
            __threadfence();      // acquire side before reading coef
            polled = true;
        }
        __syncthreads();

        // ---------- final phase: t = s*32 + k ----------
        {
            int k = t & 31;
            int s = t >> 5;

            float r0=0.f, r1=0.f, r2=0.f, r3=0.f;
            #pragma unroll 2
            for (int j = 0; j < J_; ++j) {
                const float* thp = thetau + ((s*J_ + j)*P_)*BU_ + k;
                float phi = thp[0]*t0 + thp[BU_]*t1 + thp[2*BU_]*t2;
                float sp, cp; __sincosf(phi, &sp, &cp);
                const float4* cf = (const float4*)(ws + COEF_OFF + ((s*J_ + j)*BU_ + k)*8);
                float4 u = cf[0], v = cf[1];
                r0 += u.x*cp - u.y*sp;
                r1 += u.z*cp - u.w*sp;
                r2 += v.x*cp - v.y*sp;
                r3 += v.z*cp - v.w*sp;
            }
            #pragma unroll
            for (int off = 16; off; off >>= 1) {
                r0 += __shfl_xor(r0, off, 32);
                r1 += __shfl_xor(r1, off, 32);
                r2 += __shfl_xor(r2, off, 32);
                r3 += __shfl_xor(r3, off, 32);
            }
            if (k == 0) {
                float4 o;
                o.x = scan[s][0] + r0 + t0*W[0*D_+0] + t1*W[1*D_+0] + t2*W[2*D_+0];
                o.y = scan[s][1] + r1 + t0*W[0*D_+1] + t1*W[1*D_+1] + t2*W[2*D_+1];
                o.z = scan[s][2] + r2 + t0*W[0*D_+2] + t1*W[1*D_+2] + t2*W[2*D_+2];
                o.w = scan[s][3] + r3 + t0*W[0*D_+3] + t1*W[1*D_+3] + t2*W[2*D_+3];
                *(float4*)(out + (s*N_ + n)*D_) = o;
            }
        }
        __syncthreads();
    }
}

extern "C" void kernel_launch(void* const* d_in, const int* in_sizes, int n_in,
                              void* d_out, int out_size, void* d_ws, size_t ws_size,
                              hipStream_t stream)
{
    const float* ts       = (const float*)d_in[0];
    const float* alphas   = (const float*)d_in[1];
    const float* pgs      = (const float*)d_in[2];
    const float* zgs      = (const float*)d_in[3];
    const float* thetag   = (const float*)d_in[4];
    const float* betag    = (const float*)d_in[5];
    const float* wg       = (const float*)d_in[6];
    const float* qg       = (const float*)d_in[7];
    const float* pus      = (const float*)d_in[8];
    const float* zus      = (const float*)d_in[9];
    const float* thetau   = (const float*)d_in[10];
    const float* betau    = (const float*)d_in[11];
    const float* wu       = (const float*)d_in[12];
    const float* qu       = (const float*)d_in[13];
    const float* ampu     = (const float*)d_in[14];
    const float* log_amps = (const float*)d_in[15];
    const float* W        = (const float*)d_in[16];
    float* ws  = (float*)d_ws;
    float* out = (float*)d_out;

    one_kernel<<<NBLK, 256, 0, stream>>>(
        ts, alphas, pgs, zgs, thetag, betag, wg, qg,
        pus, zus, thetau, betau, wu, qu, ampu, log_amps, W, ws, out);
}

// Round 10
// 26.028 us; speedup vs baseline: 4.0848x; 4.0848x over previous
//
#include <hip/hip_runtime.h>
#include <math.h>

#define S_ 8
#define J_ 4
#define D_ 4
#define P_ 3
#define N_ 1024
#define BG_ 32
#define BU_ 32
#define MG_ 10
#define MU_ 32

static constexpr float PI_F = 3.14159265358979323846f;

// workspace float offsets
#define COEF_OFF    0                    // [s][j][bu][d][2] = 8192
#define CANPART_OFF 8192                 // [s][n][d]        = 32768

#define NB_COEF 64                       // 16384 coef threads / 256 (FIRST in grid)
#define NB_CAN  512                      // D * N/8 blocks of 256

// ====== fused: blocks [0,64) = coef (start first, overlap), [64,576) = can ===
// can block: (d, 8 n); 256 thr = 4 waves; wave = 2q x 32m; each thread 2 n
__global__ __launch_bounds__(256, 4) void fused_kernel(
    const float* __restrict__ ts,     const float* __restrict__ alphas,
    const float* __restrict__ pgs,    const float* __restrict__ zgs,
    const float* __restrict__ thetag, const float* __restrict__ betag,
    const float* __restrict__ wg,     const float* __restrict__ qg,
    const float* __restrict__ pus,    const float* __restrict__ zus,
    const float* __restrict__ thetau, const float* __restrict__ betau,
    const float* __restrict__ wu,     const float* __restrict__ qu,
    const float* __restrict__ ampu_p, const float* __restrict__ log_amps,
    float* __restrict__ ws)
{
    int bid = blockIdx.x;
    int t   = threadIdx.x;
    float ampu = ampu_p[0];

    if (bid >= NB_COEF) {
        // ------------------------- canonical part --------------------------
        __shared__ float sc1[P_][BG_][S_];   // 768
        __shared__ float sc2[P_][BG_][S_];   // 768
        __shared__ float sqg[P_][MG_][S_];   // 240
        __shared__ float stg[P_][BG_];       // 96
        __shared__ float szg[P_][MG_];       // 30
        __shared__ float szu[P_][MU_];       // 96
        __shared__ float sts[8][P_];         // 24
        __shared__ float squ[S_][MU_];       // 256
        __shared__ float skmp[P_], skrp[P_], sksc[P_], skbc[P_];

        int cb = bid - NB_COEF;
        int d  = cb >> 7;
        int n0 = (cb & 127) * 8;

        // ---- in-block table build (amortized over 8 n) ----
        for (int i = t; i < P_*BG_*S_; i += 256) {   // sc1/sc2[p][b][s]
            int p = i >> 8, b = (i >> 3) & 31, s = i & 7;
            float alpha = alphas[d*P_ + p];
            float Bm = alpha + pus[p];
            float th = thetag[(d*P_ + p)*BG_ + b];
            float spec = sqrtf(PI_F / Bm) * __expf(-th*th*0.25f/Bm);
            float be = betag[((s*D_ + d)*P_ + p)*BG_ + b];
            float w  = wg   [((s*D_ + d)*P_ + p)*BG_ + b];
            float sb, cbv; __sincosf(be, &sb, &cbv);
            sc1[p][b][s] = w * cbv * spec;
            sc2[p][b][s] = w * sb * spec;
        }
        for (int i = t; i < P_*MG_*S_; i += 256) {   // sqg[p][g][s]
            int p = i / (MG_*S_), r = i % (MG_*S_), g = r >> 3, s = r & 7;
            ((float*)sqg)[i] = qg[((s*D_ + d)*P_ + p)*MG_ + g];
        }
        {   // squ[s][m] (quamp), 256 entries, 1/thread
            int s = t >> 5, m = t & 31;
            float acc = 0.f;
            #pragma unroll
            for (int j = 0; j < J_; ++j)
                acc += __expf(log_amps[d*J_ + j]) * qu[(s*J_ + j)*MU_ + m];
            squ[s][m] = ampu * acc;
        }
        if (t < P_*BG_) ((float*)stg)[t] = thetag[d*P_*BG_ + t];
        if (t < P_*MG_) { int p = t / MG_, g = t % MG_; szg[p][g] = zgs[g*P_ + p]; }
        if (t >= 128 && t < 128 + P_*MU_) {
            int i = t - 128; int p = i >> 5, m = i & 31;
            szu[p][m] = zus[m*P_ + p];
        }
        if (t >= 96 && t < 96 + 8*P_) { int i = t - 96; sts[i/3][i%3] = ts[n0*P_ + i]; }
        if (t >= 120 && t < 120 + P_) {
            int p = t - 120;
            float alpha = alphas[d*P_ + p], pg = pgs[d*P_ + p], pu = pus[p];
            float Bm = alpha + pu, invB = 1.f / Bm;
            skmp[p] = pu * invB;
            skrp[p] = alpha * pu * invB;
            float Cm = Bm + pg, invC = 1.f / Cm;
            sksc[p] = sqrtf(PI_F * invC);
            skbc[p] = Bm * pg * invC;
        }
        __syncthreads();

        int m = t & 31, q = (t >> 5) & 1, nl = t >> 6;
        // this thread's two n values: n0 + nl*2 + {0,1}
        int rA = nl*2, rB = nl*2 + 1;

        float pA0=1.f,pA1=1.f,pA2=1.f,pA3=1.f,pA4=1.f,pA5=1.f,pA6=1.f,pA7=1.f;
        float pB0=1.f,pB1=1.f,pB2=1.f,pB3=1.f,pB4=1.f,pB5=1.f,pB6=1.f,pB7=1.f;

        #pragma unroll 1
        for (int p = 0; p < P_; ++p) {
            float zu = szu[p][m];
            float cA = sts[rA][p] - zu;
            float cB = sts[rB][p] - zu;
            float mpA = skmp[p] * cA, mpB = skmp[p] * cB;
            float EA = __expf(-skrp[p] * cA * cA);
            float EB = __expf(-skrp[p] * cB * cB);

            float aA0=0.f,aA1=0.f,aA2=0.f,aA3=0.f,aA4=0.f,aA5=0.f,aA6=0.f,aA7=0.f;
            float aB0=0.f,aB1=0.f,aB2=0.f,aB3=0.f,aB4=0.f,aB5=0.f,aB6=0.f,aB7=0.f;

            int b0 = q * 16;
            #pragma unroll 2
            for (int bb = 0; bb < 16; ++bb) {
                int b = b0 + bb;
                float th = stg[p][b];
                float sxA, cxA; __sincosf(th * mpA, &sxA, &cxA);
                float sxB, cxB; __sincosf(th * mpB, &sxB, &cxB);
                const float4* c1v = (const float4*)&sc1[p][b][0];
                const float4* c2v = (const float4*)&sc2[p][b][0];
                float4 u0 = c1v[0], u1 = c1v[1];
                float4 v0 = c2v[0], v1 = c2v[1];
                aA0 += u0.x*cxA - v0.x*sxA;  aA1 += u0.y*cxA - v0.y*sxA;
                aA2 += u0.z*cxA - v0.z*sxA;  aA3 += u0.w*cxA - v0.w*sxA;
                aA4 += u1.x*cxA - v1.x*sxA;  aA5 += u1.y*cxA - v1.y*sxA;
                aA6 += u1.z*cxA - v1.z*sxA;  aA7 += u1.w*cxA - v1.w*sxA;
                aB0 += u0.x*cxB - v0.x*sxB;  aB1 += u0.y*cxB - v0.y*sxB;
                aB2 += u0.z*cxB - v0.z*sxB;  aB3 += u0.w*cxB - v0.w*sxB;
                aB4 += u1.x*cxB - v1.x*sxB;  aB5 += u1.y*cxB - v1.y*sxB;
                aB6 += u1.z*cxB - v1.z*sxB;  aB7 += u1.w*cxB - v1.w*sxB;
            }
            int g0 = q * 5;
            #pragma unroll 1
            for (int gg = 0; gg < 5; ++gg) {
                int g = g0 + gg;
                float zg = szg[p][g];
                float dA = mpA - zg, dB = mpB - zg;
                float vA = sksc[p] * __expf(-skbc[p]*dA*dA);
                float vB = sksc[p] * __expf(-skbc[p]*dB*dB);
                const float4* qv = (const float4*)&sqg[p][g][0];
                float4 q0 = qv[0], q1 = qv[1];
                aA0 += q0.x*vA; aA1 += q0.y*vA; aA2 += q0.z*vA; aA3 += q0.w*vA;
                aA4 += q1.x*vA; aA5 += q1.y*vA; aA6 += q1.z*vA; aA7 += q1.w*vA;
                aB0 += q0.x*vB; aB1 += q0.y*vB; aB2 += q0.z*vB; aB3 += q0.w*vB;
                aB4 += q1.x*vB; aB5 += q1.y*vB; aB6 += q1.z*vB; aB7 += q1.w*vB;
            }
            // combine q-halves (partner = lane ^ 32 within the wave)
            aA0 += __shfl_xor(aA0, 32, 64); aA1 += __shfl_xor(aA1, 32, 64);
            aA2 += __shfl_xor(aA2, 32, 64); aA3 += __shfl_xor(aA3, 32, 64);
            aA4 += __shfl_xor(aA4, 32, 64); aA5 += __shfl_xor(aA5, 32, 64);
            aA6 += __shfl_xor(aA6, 32, 64); aA7 += __shfl_xor(aA7, 32, 64);
            aB0 += __shfl_xor(aB0, 32, 64); aB1 += __shfl_xor(aB1, 32, 64);
            aB2 += __shfl_xor(aB2, 32, 64); aB3 += __shfl_xor(aB3, 32, 64);
            aB4 += __shfl_xor(aB4, 32, 64); aB5 += __shfl_xor(aB5, 32, 64);
            aB6 += __shfl_xor(aB6, 32, 64); aB7 += __shfl_xor(aB7, 32, 64);
            pA0 *= EA*aA0; pA1 *= EA*aA1; pA2 *= EA*aA2; pA3 *= EA*aA3;
            pA4 *= EA*aA4; pA5 *= EA*aA5; pA6 *= EA*aA6; pA7 *= EA*aA7;
            pB0 *= EB*aB0; pB1 *= EB*aB1; pB2 *= EB*aB2; pB3 *= EB*aB3;
            pB4 *= EB*aB4; pB5 *= EB*aB5; pB6 *= EB*aB6; pB7 *= EB*aB7;
        }

        // s-reduce split across q-halves: q=0 -> s0..3, q=1 -> s4..7
        float prodA[S_] = {pA0,pA1,pA2,pA3,pA4,pA5,pA6,pA7};
        float prodB[S_] = {pB0,pB1,pB2,pB3,pB4,pB5,pB6,pB7};
        int nA = n0 + rA, nB = n0 + rB;
        int s0 = q * 4;
        #pragma unroll
        for (int ss = 0; ss < 4; ++ss) {
            int s = ss + s0;
            float qu_sm = squ[s][m];
            float vA = qu_sm * prodA[s];
            float vB = qu_sm * prodB[s];
            #pragma unroll
            for (int off = 16; off; off >>= 1) {
                vA += __shfl_xor(vA, off, 32);
                vB += __shfl_xor(vB, off, 32);
            }
            if (m == 0) {
                ws[CANPART_OFF + (s*N_ + nA)*D_ + d] = vA;
                ws[CANPART_OFF + (s*N_ + nB)*D_ + d] = vB;
            }
        }
    } else {
        // ---- coef: Ghat -> G3 -> coef; 4-lane split over (b,g) sums ----
        int gtid = bid * 256 + t;                   // [0, 16384)
        int q  = gtid & 3;
        int bu = (gtid >> 2) & 31;
        int d  = (gtid >> 7) & 3;
        int j  = (gtid >> 9) & 3;
        int s  = gtid >> 11;
        float G3r = 1.f, G3i = 0.f;
        #pragma unroll 1
        for (int p = 0; p < P_; ++p) {
            float alpha = alphas[d*P_ + p], pg = pgs[d*P_ + p];
            float om    = thetau[((s*J_ + j)*P_ + p)*BU_ + bu];
            float inv4a = 0.25f / alpha;
            float pref  = 0.5f * sqrtf(PI_F / alpha);
            float gr = 0.f, gi = 0.f;
            int b0 = q * 8;
            #pragma unroll 2
            for (int bb = 0; bb < 8; ++bb) {
                int b = b0 + bb;
                float th = thetag[(d*P_ + p)*BG_ + b];
                float dm = th - om, dpl = th + om;
                float e1 = __expf(-dm*dm*inv4a);
                float e2 = __expf(-dpl*dpl*inv4a);
                float be = betag[((s*D_ + d)*P_ + p)*BG_ + b];
                float w  = wg   [((s*D_ + d)*P_ + p)*BG_ + b];
                float sb, cb; __sincosf(be, &sb, &cb);
                gr += pref * w * (e1 + e2) * cb;
                gi += pref * w * (e1 - e2) * sb;
            }
            float A = alpha + pg, invA = 1.f / A;
            float decay = __expf(-om*om*0.25f*invA);
            float cc    = sqrtf(PI_F * invA);
            float cr = 0.f, ci = 0.f;
            int g0 = q * 3, gn = (q < 3) ? 3 : 1;
            #pragma unroll 1
            for (int gg = 0; gg < gn; ++gg) {
                int g = g0 + gg;
                float z  = zgs[g*P_ + p];
                float mu = pg * z * invA;
                float rg = alpha * pg * z * z * invA;
                float cg = cc * __expf(-rg);
                float qv = qg[((s*D_ + d)*P_ + p)*MG_ + g];
                float sm, cm; __sincosf(om * mu, &sm, &cm);
                cr += qv * cg * cm;
                ci -= qv * cg * sm;
            }
            #pragma unroll
            for (int off = 1; off < 4; off <<= 1) {
                gr += __shfl_xor(gr, off, 4);
                gi += __shfl_xor(gi, off, 4);
                cr += __shfl_xor(cr, off, 4);
                ci += __shfl_xor(ci, off, 4);
            }
            float Gr = gr + decay * cr;
            float Gi = gi + decay * ci;
            float nr = G3r*Gr - G3i*Gi;
            float ni = G3r*Gi + G3i*Gr;
            G3r = nr; G3i = ni;
        }
        if (q == 0) {
            float bv = betau[(s*J_ + j)*BU_ + bu];
            float wv = wu   [(s*J_ + j)*BU_ + bu];
            float sbu, cbu; __sincosf(bv, &sbu, &cbu);
            float cuR = wv * cbu, cuI = wv * sbu;
            float amp = ampu * __expf(log_amps[d*J_ + j]);
            int base = (((s*J_ + j)*BU_ + bu)*D_ + d) * 2;
            ws[COEF_OFF + base    ] = amp * (cuR*G3r - cuI*G3i);
            ws[COEF_OFF + base + 1] = amp * (cuR*G3i + cuI*G3r);
        }
    }
}

// ---------------- final: F_rff + canpart + ts@W ------------------------------
// block = (s, 8 n); 256 thr = 8 nl x 32 k; each lane does 4 (j,bu=k) pairs
__global__ __launch_bounds__(256, 4) void final_kernel(
    const float* __restrict__ ts, const float* __restrict__ thetau,
    const float* __restrict__ W,  const float* __restrict__ ws,
    float* __restrict__ out)
{
    __shared__ float sth[J_][P_][BU_];   // 384
    __shared__ float scf[J_*BU_][8];     // 1024
    __shared__ float sW[P_][D_];         // 12

    int bid = blockIdx.x;                // S * N/8 = 1024
    int s  = bid >> 7;
    int n0 = (bid & 127) * 8;
    int t  = threadIdx.x;

    for (int i = t; i < J_*P_*BU_; i += 256) ((float*)sth)[i] = thetau[s*J_*P_*BU_ + i];
    for (int i = t; i < J_*BU_*8; i += 256)  ((float*)scf)[i] = ws[COEF_OFF + s*J_*BU_*8 + i];
    if (t < P_*D_) ((float*)sW)[t] = W[t];
    __syncthreads();

    int k = t & 31, nl = t >> 5;
    int n = n0 + nl;
    float t0 = ts[n*P_], t1 = ts[n*P_ + 1], t2 = ts[n*P_ + 2];

    float r0=0.f, r1=0.f, r2=0.f, r3=0.f;
    #pragma unroll 2
    for (int j = 0; j < J_; ++j) {
        float phi = sth[j][0][k]*t0 + sth[j][1][k]*t1 + sth[j][2][k]*t2;
        float sp, cp; __sincosf(phi, &sp, &cp);
        const float4* cfv = (const float4*)&scf[j*BU_ + k][0];
        float4 u = cfv[0], v = cfv[1];
        r0 += u.x*cp - u.y*sp;
        r1 += u.z*cp - u.w*sp;
        r2 += v.x*cp - v.y*sp;
        r3 += v.z*cp - v.w*sp;
    }
    #pragma unroll
    for (int off = 16; off; off >>= 1) {
        r0 += __shfl_xor(r0, off, 32);
        r1 += __shfl_xor(r1, off, 32);
        r2 += __shfl_xor(r2, off, 32);
        r3 += __shfl_xor(r3, off, 32);
    }
    if (k == 0) {
        const float4 cpart = *(const float4*)(ws + CANPART_OFF + (s*N_ + n)*D_);
        float4 o;
        o.x = cpart.x + r0 + t0*sW[0][0] + t1*sW[1][0] + t2*sW[2][0];
        o.y = cpart.y + r1 + t0*sW[0][1] + t1*sW[1][1] + t2*sW[2][1];
        o.z = cpart.z + r2 + t0*sW[0][2] + t1*sW[1][2] + t2*sW[2][2];
        o.w = cpart.w + r3 + t0*sW[0][3] + t1*sW[1][3] + t2*sW[2][3];
        *(float4*)(out + (s*N_ + n)*D_) = o;
    }
}

extern "C" void kernel_launch(void* const* d_in, const int* in_sizes, int n_in,
                              void* d_out, int out_size, void* d_ws, size_t ws_size,
                              hipStream_t stream)
{
    const float* ts       = (const float*)d_in[0];
    const float* alphas   = (const float*)d_in[1];
    const float* pgs      = (const float*)d_in[2];
    const float* zgs      = (const float*)d_in[3];
    const float* thetag   = (const float*)d_in[4];
    const float* betag    = (const float*)d_in[5];
    const float* wg       = (const float*)d_in[6];
    const float* qg       = (const float*)d_in[7];
    const float* pus      = (const float*)d_in[8];
    const float* zus      = (const float*)d_in[9];
    const float* thetau   = (const float*)d_in[10];
    const float* betau    = (const float*)d_in[11];
    const float* wu       = (const float*)d_in[12];
    const float* qu       = (const float*)d_in[13];
    const float* ampu     = (const float*)d_in[14];
    const float* log_amps = (const float*)d_in[15];
    const float* W        = (const float*)d_in[16];
    float* ws  = (float*)d_ws;
    float* out = (float*)d_out;

    fused_kernel<<<NB_COEF + NB_CAN, 256, 0, stream>>>(
        ts, alphas, pgs, zgs, thetag, betag, wg, qg,
        pus, zus, thetau, betau, wu, qu, ampu, log_amps, ws);
    final_kernel<<<1024, 256, 0, stream>>>(ts, thetau, W, ws, out);
}